// Round 12
// baseline (170.964 us; speedup 1.0000x reference)
//
#include <hip/hip_runtime.h>
#include <hip/hip_fp16.h>
#include <math.h>

#define DH 128
#define CAPW 128
#define GRPS 4
#define NSUB 64
#define SUPER (NSUB * 256)     // 16384: edge-share super-block (hist & scatter MUST match)
#define HCHUNK 12800

__device__ __forceinline__ float waveSum(float x) {
    #pragma unroll
    for (int m = 32; m; m >>= 1) x += __shfl_xor(x, m);
    return x;
}
__device__ __forceinline__ unsigned waveSumU(unsigned x) {
    #pragma unroll
    for (int m = 32; m; m >>= 1) x += __shfl_xor(x, m);
    return x;
}

// fdot2: f32 += a(h2).b(h2) via v_dot2_f32_f16 when available.
__device__ __forceinline__ float fdot2f(__half2 a, __half2 b, float c) {
#if __has_builtin(__builtin_amdgcn_fdot2)
    typedef _Float16 v2h __attribute__((ext_vector_type(2)));
    v2h av, bv;
    __builtin_memcpy(&av, &a, 4);
    __builtin_memcpy(&bv, &b, 4);
    return __builtin_amdgcn_fdot2(av, bv, c, false);
#else
    float2 af = __half22float2(a), bf = __half22float2(b);
    return c + af.x * bf.x + af.y * bf.y;
#endif
}

__device__ __forceinline__ float edgeW(float ui, float vd, float ab) {
    float C = fmaxf(ui + ab, 0.f);
    float lg = ui + vd + ab;
    lg = lg >= 0.f ? lg : 0.01f * lg;
    return __expf(fminf(lg - C, 10.f));
}

// K1: FUSED. Blocks [0,nb): GEMM h=x@W+b (fp16 k-pair staging, dot2, f32 acc; u,v in
// epilogue). Blocks [nb, nb+GRPS*NSUB): per-(group,sub) LDS histogram -> hsub (ushort).
// Independent roles share one launch so VALU-bound GEMM hides the memory-bound hist.
__global__ __launch_bounds__(256) void k_mmhist(
    const float* __restrict__ x, const float* __restrict__ Wg,
    const float* __restrict__ bg, const float* __restrict__ ag,
    const int* __restrict__ ei, int E,
    __half2* __restrict__ h2, float* __restrict__ u, float* __restrict__ v,
    unsigned short* __restrict__ hsub, int n, int nb)
{
    __shared__ union {
        struct {
            __half2 Wsp[64][132];   // {W[2k2][c], W[2k2+1][c]}
            __half2 Xs2[64][68];    // {x[r][2k2], x[r][2k2+1]}
            float as_s[128], ad_s[128];
        } mm;
        unsigned hist[HCHUNK];
    } shm;
    int t = threadIdx.x;

    if ((int)blockIdx.x < nb) {
        // ---------- matmul role ----------
        int row0 = blockIdx.x * 64;
        const float4* W4 = (const float4*)Wg;
        for (int i = t; i < 2048; i += 256) {
            int k2 = i >> 5, c4 = i & 31;
            float4 a = W4[(2 * k2) * 32 + c4];
            float4 b = W4[(2 * k2 + 1) * 32 + c4];
            shm.mm.Wsp[k2][c4 * 4 + 0] = __floats2half2_rn(a.x, b.x);
            shm.mm.Wsp[k2][c4 * 4 + 1] = __floats2half2_rn(a.y, b.y);
            shm.mm.Wsp[k2][c4 * 4 + 2] = __floats2half2_rn(a.z, b.z);
            shm.mm.Wsp[k2][c4 * 4 + 3] = __floats2half2_rn(a.w, b.w);
        }
        const float4* x4 = (const float4*)x;
        for (int i = t; i < 2048; i += 256) {
            int r = i >> 5, c4 = i & 31;
            int gr = row0 + r;
            float4 xv = (gr < n) ? x4[(size_t)gr * 32 + c4] : float4{0.f, 0.f, 0.f, 0.f};
            shm.mm.Xs2[r][c4 * 2]     = __floats2half2_rn(xv.x, xv.y);
            shm.mm.Xs2[r][c4 * 2 + 1] = __floats2half2_rn(xv.z, xv.w);
        }
        if (t < 128) { shm.mm.as_s[t] = ag[t]; shm.mm.ad_s[t] = ag[128 + t]; }
        __syncthreads();

        int tcol = t & 15, trow = t >> 4;
        int c0 = tcol * 8, r0 = trow * 4;
        float acc[4][8] = {};
        for (int k2 = 0; k2 < 64; ++k2) {
            __half2 wp[8];
            const __half2* wrow = &shm.mm.Wsp[k2][c0];
            #pragma unroll
            for (int j = 0; j < 8; ++j) wp[j] = wrow[j];
            __half2 xv0 = shm.mm.Xs2[r0 + 0][k2];
            __half2 xv1 = shm.mm.Xs2[r0 + 1][k2];
            __half2 xv2 = shm.mm.Xs2[r0 + 2][k2];
            __half2 xv3 = shm.mm.Xs2[r0 + 3][k2];
            #pragma unroll
            for (int j = 0; j < 8; ++j) {
                acc[0][j] = fdot2f(xv0, wp[j], acc[0][j]);
                acc[1][j] = fdot2f(xv1, wp[j], acc[1][j]);
                acc[2][j] = fdot2f(xv2, wp[j], acc[2][j]);
                acc[3][j] = fdot2f(xv3, wp[j], acc[3][j]);
            }
        }
        float bf[8], asv[8], adv[8];
        #pragma unroll
        for (int j = 0; j < 8; ++j) {
            bf[j] = bg[c0 + j];
            asv[j] = shm.mm.as_s[c0 + j];
            adv[j] = shm.mm.ad_s[c0 + j];
        }
        #pragma unroll
        for (int r = 0; r < 4; ++r) {
            int gr = row0 + r0 + r;
            float ov[8];
            float pu = 0.f, pv = 0.f;
            #pragma unroll
            for (int j = 0; j < 8; ++j) {
                ov[j] = acc[r][j] + bf[j];
                pu += ov[j] * asv[j];
                pv += ov[j] * adv[j];
            }
            if (gr < n) {
                __half2* hp = h2 + (size_t)gr * 64 + (c0 >> 1);
                #pragma unroll
                for (int j = 0; j < 4; ++j)
                    hp[j] = __floats2half2_rn(ov[2 * j], ov[2 * j + 1]);
            }
            #pragma unroll
            for (int m = 1; m <= 8; m <<= 1) {
                pu += __shfl_xor(pu, m);
                pv += __shfl_xor(pv, m);
            }
            if (tcol == 0 && gr < n) { u[gr] = pu; v[gr] = pv; }
        }
    } else {
        // ---------- histogram role ----------
        int hb  = blockIdx.x - nb;
        int grp = hb & (GRPS - 1);
        int sub = hb / GRPS;
        int lo = (int)((long long)grp * n / GRPS);
        int hi = (int)((long long)(grp + 1) * n / GRPS);
        for (int base = lo; base < hi; base += HCHUNK) {
            int clen = min(HCHUNK, hi - base);
            for (int i = t; i < clen; i += 256) shm.hist[i] = 0u;
            __syncthreads();
            for (int e = sub * 256 + t; e < E; e += SUPER) {
                int s = ei[e];
                if (s >= base && s < base + clen) atomicAdd(&shm.hist[s - base], 1u);
            }
            __syncthreads();
            for (int i = t; i < clen; i += 256)
                hsub[(size_t)sub * n + base + i] = (unsigned short)shm.hist[i];
            __syncthreads();
        }
    }
}

// K2: per-256-node-block totals (1 self-loop + sum over subs) -> psum
__global__ void k_scan_partial(const unsigned short* __restrict__ hsub,
                               unsigned* __restrict__ psum, int n) {
    __shared__ unsigned s[256];
    int t = threadIdx.x, idx = blockIdx.x * 256 + t;
    unsigned c = 0u;
    if (idx < n) {
        c = 1u;
        for (int sb = 0; sb < NSUB; ++sb) c += hsub[(size_t)sb * n + idx];
    }
    s[t] = c;
    __syncthreads();
    for (int d = 128; d; d >>= 1) { if (t < d) s[t] += s[t + d]; __syncthreads(); }
    if (t == 0) psum[blockIdx.x] = s[0];
}

// K3: exclusive scan -> off; per-sub ushort DELTAS basepu (slot 0 = self-loop);
// packed self-loop entry {idx, w_self} written to edstP[off[idx]].
__global__ void k_scan_final(const unsigned* __restrict__ psum,
                             const unsigned short* __restrict__ hsub,
                             const float* __restrict__ u, const float* __restrict__ v,
                             const float* __restrict__ ab_p,
                             unsigned* __restrict__ off, unsigned short* __restrict__ basepu,
                             unsigned* __restrict__ edstP, int n) {
    __shared__ unsigned s[256];
    __shared__ unsigned wred[4];
    int t = threadIdx.x, idx = blockIdx.x * 256 + t;
    unsigned p = (t < blockIdx.x) ? psum[t] : 0u;
    p = waveSumU(p);
    if ((t & 63) == 0) wred[t >> 6] = p;
    __syncthreads();
    unsigned base = wred[0] + wred[1] + wred[2] + wred[3];

    unsigned run = 0u;
    if (idx < n) {
        run = 1u;                                  // slot 0: self-loop
        for (int sb = 0; sb < NSUB; ++sb) {
            basepu[(size_t)sb * n + idx] = (unsigned short)run;
            run += hsub[(size_t)sb * n + idx];
        }
    }
    s[t] = run; __syncthreads();
    for (int d = 1; d < 256; d <<= 1) {
        unsigned xx = (t >= d) ? s[t - d] : 0u;
        __syncthreads();
        s[t] += xx;
        __syncthreads();
    }
    unsigned excl = s[t] - run + base;
    if (idx < n) {
        off[idx] = excl;
        if (idx == n - 1) off[n] = excl + run;
        float wv = edgeW(u[idx], v[idx], ab_p[0]);
        unsigned short wh = __half_as_ushort(__float2half_rn(wv));
        edstP[excl] = (unsigned)idx | ((unsigned)wh << 16);   // n<=65536 required
    }
}

// K4: atomic-free scatter; packs {ushort d, half w} per edge. LDS cursors =
// off + basepu delta. Edge share per (grp,sub) MUST equal hist's share.
__global__ __launch_bounds__(1024) void k_scatter(
    const int* __restrict__ ei, int E, int n,
    const unsigned* __restrict__ off, const unsigned short* __restrict__ basepu,
    const float* __restrict__ u, const float* __restrict__ v,
    const float* __restrict__ ab_p, unsigned* __restrict__ edstP)
{
    __shared__ unsigned cur[HCHUNK];
    int grp = blockIdx.x & (GRPS - 1);
    int sub = blockIdx.x / GRPS;
    int t = threadIdx.x;
    float ab = ab_p[0];
    int lo = (int)((long long)grp * n / GRPS);
    int hi = (int)((long long)(grp + 1) * n / GRPS);
    int tlo = t & 255, thi = t >> 8;
    for (int base = lo; base < hi; base += HCHUNK) {
        int clen = min(HCHUNK, hi - base);
        for (int i = t; i < clen; i += 1024)
            cur[i] = off[base + i] + basepu[(size_t)sub * n + base + i];
        __syncthreads();
        for (int e = sub * 256 + tlo + thi * SUPER; e < E; e += 4 * SUPER) {
            int s = ei[e];
            int d = ei[E + e];               // coalesced, unconditional
            if (s >= base && s < base + clen) {
                float wv = edgeW(u[s], v[d], ab);
                unsigned short wh = __half_as_ushort(__float2half_rn(wv));
                unsigned p = atomicAdd(&cur[s - base], 1u);   // LDS atomic only
                edstP[p] = (unsigned)d | ((unsigned)wh << 16);
            }
        }
        __syncthreads();
    }
}

// K5: one WAVE per node, 4 nodes/block, barrier-free. Weights precomputed:
// pass1 = coalesced read + sum (no gather, no exp); pass2 = h gather + packed fp16 fma.
__global__ __launch_bounds__(256) void k_agg(
    const unsigned* __restrict__ edstP, const unsigned* __restrict__ off,
    const __half2* __restrict__ h2, float* __restrict__ out, int n)
{
    __shared__ unsigned ps[4][CAPW];
    int t = threadIdx.x;
    int wave = t >> 6, lane = t & 63;
    int i = blockIdx.x * 4 + wave;
    if (i >= n) return;
    unsigned s0 = off[i];
    int deg = (int)(off[i + 1] - s0);

    float sm = 0.f;
    for (int e = lane; e < deg; e += 64) {
        unsigned p = edstP[s0 + e];
        if (e < CAPW) ps[wave][e] = p;
        sm += __half2float(__ushort_as_half((unsigned short)(p >> 16)));
    }
    sm = waveSum(sm);
    float inv = 1.f / sm;

    int g = lane >> 4, gl = lane & 15;
    __half2 accA[4], accB[4];
    #pragma unroll
    for (int k = 0; k < 4; ++k) { accA[k] = __float2half2_rn(0.f); accB[k] = __float2half2_rn(0.f); }

    for (int e = g; e < deg; e += 8) {
        {
            unsigned p = (e < CAPW) ? ps[wave][e] : edstP[s0 + e];
            int d = (int)(p & 0xFFFFu);
            __half wv = __ushort_as_half((unsigned short)(p >> 16));
            __half2 wh = __half2half2(wv);
            float4 raw = ((const float4*)(h2 + (size_t)d * 64))[gl];
            const __half2* hp = (const __half2*)&raw;
            #pragma unroll
            for (int k = 0; k < 4; ++k) accA[k] = __hfma2(wh, hp[k], accA[k]);
        }
        int e2 = e + 4;
        if (e2 < deg) {
            unsigned p = (e2 < CAPW) ? ps[wave][e2] : edstP[s0 + e2];
            int d = (int)(p & 0xFFFFu);
            __half wv = __ushort_as_half((unsigned short)(p >> 16));
            __half2 wh = __half2half2(wv);
            float4 raw = ((const float4*)(h2 + (size_t)d * 64))[gl];
            const __half2* hp = (const __half2*)&raw;
            #pragma unroll
            for (int k = 0; k < 4; ++k) accB[k] = __hfma2(wh, hp[k], accB[k]);
        }
    }
    float acc[8];
    #pragma unroll
    for (int k = 0; k < 4; ++k) {
        float2 fa = __half22float2(accA[k]);
        float2 fb = __half22float2(accB[k]);
        acc[2 * k]     = fa.x + fb.x;
        acc[2 * k + 1] = fa.y + fb.y;
    }
    #pragma unroll
    for (int k = 0; k < 8; ++k) {
        acc[k] += __shfl_xor(acc[k], 16);
        acc[k] += __shfl_xor(acc[k], 32);
    }
    if (g == 0) {
        float o[8];
        #pragma unroll
        for (int k = 0; k < 8; ++k) {
            float z = acc[k] * inv;
            o[k] = z > 0.f ? z : expm1f(z);
        }
        float4* orow = (float4*)(out + (size_t)i * DH);
        orow[gl * 2]     = float4{o[0], o[1], o[2], o[3]};
        orow[gl * 2 + 1] = float4{o[4], o[5], o[6], o[7]};
    }
}

extern "C" void kernel_launch(void* const* d_in, const int* in_sizes, int n_in,
                              void* d_out, int out_size, void* d_ws, size_t ws_size,
                              hipStream_t stream) {
    const float* x  = (const float*)d_in[0];
    const int*   ei = (const int*)d_in[1];
    const float* W  = (const float*)d_in[2];
    const float* b  = (const float*)d_in[3];
    const float* a  = (const float*)d_in[4];
    const float* ab = (const float*)d_in[5];
    float* out = (float*)d_out;
    int n  = in_sizes[0] / DH;    // 50000 (packed ushort d requires n <= 65536)
    int E  = in_sizes[1] / 2;
    int ET = E + n;

    char* w = (char*)d_ws;
    __half2*        h2     = (__half2*)w;         w += (size_t)n * DH * 2;
    float*          u      = (float*)w;           w += (size_t)n * 4;
    float*          v      = (float*)w;           w += (size_t)n * 4;
    unsigned*       off    = (unsigned*)w;        w += (size_t)(n + 1) * 4 + 4;
    unsigned*       edstP  = (unsigned*)w;        w += (size_t)ET * 4;
    unsigned*       psum   = (unsigned*)w;        w += 4096;
    unsigned short* hsub   = (unsigned short*)w;  w += (size_t)NSUB * n * 2;
    unsigned short* basepu = (unsigned short*)w;  w += (size_t)NSUB * n * 2;

    int nb = (n + 63) / 64;
    // fused GEMM + histogram (hist blocks appended after the nb matmul blocks)
    k_mmhist<<<nb + GRPS * NSUB, 256, 0, stream>>>(x, W, b, a, ei, E, h2, u, v, hsub, n, nb);

    int B = (n + 255) / 256;
    k_scan_partial<<<B, 256, 0, stream>>>(hsub, psum, n);
    k_scan_final<<<B, 256, 0, stream>>>(psum, hsub, u, v, ab, off, basepu, edstP, n);

    // grid = GRPS*NSUB; edge shares must match k_mmhist's hist role
    k_scatter<<<GRPS * NSUB, 1024, 0, stream>>>(ei, E, n, off, basepu, u, v, ab, edstP);

    k_agg<<<(n + 3) / 4, 256, 0, stream>>>(edstP, off, h2, out, n);
}

// Round 13
// 147.424 us; speedup vs baseline: 1.1597x; 1.1597x over previous
//
#include <hip/hip_runtime.h>
#include <hip/hip_fp16.h>
#include <math.h>

#define DH 128
#define CAPW 128
#define GRPS 4
#define NSUB 64
#define SUPER (NSUB * 1024)    // 65536: edge-share super-block (hist & scatter MUST match)
#define HCHUNK 12800

__device__ __forceinline__ float waveSum(float x) {
    #pragma unroll
    for (int m = 32; m; m >>= 1) x += __shfl_xor(x, m);
    return x;
}
__device__ __forceinline__ unsigned waveSumU(unsigned x) {
    #pragma unroll
    for (int m = 32; m; m >>= 1) x += __shfl_xor(x, m);
    return x;
}

// fdot2: f32 += a(h2).b(h2) via v_dot2_f32_f16 when available.
__device__ __forceinline__ float fdot2f(__half2 a, __half2 b, float c) {
#if __has_builtin(__builtin_amdgcn_fdot2)
    typedef _Float16 v2h __attribute__((ext_vector_type(2)));
    v2h av, bv;
    __builtin_memcpy(&av, &a, 4);
    __builtin_memcpy(&bv, &b, 4);
    return __builtin_amdgcn_fdot2(av, bv, c, false);
#else
    float2 af = __half22float2(a), bf = __half22float2(b);
    return c + af.x * bf.x + af.y * bf.y;
#endif
}

__device__ __forceinline__ float edgeW(float ui, float vd, float ab) {
    float C = fmaxf(ui + ab, 0.f);
    float lg = ui + vd + ab;
    lg = lg >= 0.f ? lg : 0.01f * lg;
    return __expf(fminf(lg - C, 10.f));
}

// K1: GEMM via dot2: h = x@W + b (fp16 k-pair staging, f32 acc, stored fp16);
// u = h.a_src, v = h.a_dst in the epilogue (shfl reduce over 16 col-threads).
__global__ __launch_bounds__(256) void k_matmul(
    const float* __restrict__ x, const float* __restrict__ Wg,
    const float* __restrict__ bg, const float* __restrict__ ag,
    __half2* __restrict__ h2, float* __restrict__ u, float* __restrict__ v, int n)
{
    __shared__ __half2 Wsp[64][132];   // {W[2k2][c], W[2k2+1][c]}
    __shared__ __half2 Xs2[64][68];    // {x[r][2k2], x[r][2k2+1]}
    __shared__ float as_s[128], ad_s[128];
    int t = threadIdx.x;
    int row0 = blockIdx.x * 64;

    const float4* W4 = (const float4*)Wg;
    for (int i = t; i < 2048; i += 256) {
        int k2 = i >> 5, c4 = i & 31;
        float4 a = W4[(2 * k2) * 32 + c4];
        float4 b = W4[(2 * k2 + 1) * 32 + c4];
        Wsp[k2][c4 * 4 + 0] = __floats2half2_rn(a.x, b.x);
        Wsp[k2][c4 * 4 + 1] = __floats2half2_rn(a.y, b.y);
        Wsp[k2][c4 * 4 + 2] = __floats2half2_rn(a.z, b.z);
        Wsp[k2][c4 * 4 + 3] = __floats2half2_rn(a.w, b.w);
    }
    const float4* x4 = (const float4*)x;
    for (int i = t; i < 2048; i += 256) {
        int r = i >> 5, c4 = i & 31;
        int gr = row0 + r;
        float4 xv = (gr < n) ? x4[(size_t)gr * 32 + c4] : float4{0.f, 0.f, 0.f, 0.f};
        Xs2[r][c4 * 2]     = __floats2half2_rn(xv.x, xv.y);
        Xs2[r][c4 * 2 + 1] = __floats2half2_rn(xv.z, xv.w);
    }
    if (t < 128) { as_s[t] = ag[t]; ad_s[t] = ag[128 + t]; }
    __syncthreads();

    int tcol = t & 15, trow = t >> 4;
    int c0 = tcol * 8, r0 = trow * 4;
    float acc[4][8] = {};
    for (int k2 = 0; k2 < 64; ++k2) {
        __half2 wp[8];
        const __half2* wrow = &Wsp[k2][c0];
        #pragma unroll
        for (int j = 0; j < 8; ++j) wp[j] = wrow[j];
        __half2 xv0 = Xs2[r0 + 0][k2];
        __half2 xv1 = Xs2[r0 + 1][k2];
        __half2 xv2 = Xs2[r0 + 2][k2];
        __half2 xv3 = Xs2[r0 + 3][k2];
        #pragma unroll
        for (int j = 0; j < 8; ++j) {
            acc[0][j] = fdot2f(xv0, wp[j], acc[0][j]);
            acc[1][j] = fdot2f(xv1, wp[j], acc[1][j]);
            acc[2][j] = fdot2f(xv2, wp[j], acc[2][j]);
            acc[3][j] = fdot2f(xv3, wp[j], acc[3][j]);
        }
    }
    float bf[8], asv[8], adv[8];
    #pragma unroll
    for (int j = 0; j < 8; ++j) {
        bf[j] = bg[c0 + j];
        asv[j] = as_s[c0 + j];
        adv[j] = ad_s[c0 + j];
    }
    #pragma unroll
    for (int r = 0; r < 4; ++r) {
        int gr = row0 + r0 + r;
        float ov[8];
        float pu = 0.f, pv = 0.f;
        #pragma unroll
        for (int j = 0; j < 8; ++j) {
            ov[j] = acc[r][j] + bf[j];
            pu += ov[j] * asv[j];
            pv += ov[j] * adv[j];
        }
        if (gr < n) {
            __half2* hp = h2 + (size_t)gr * 64 + (c0 >> 1);
            #pragma unroll
            for (int j = 0; j < 4; ++j)
                hp[j] = __floats2half2_rn(ov[2 * j], ov[2 * j + 1]);
        }
        #pragma unroll
        for (int m = 1; m <= 8; m <<= 1) {
            pu += __shfl_xor(pu, m);
            pv += __shfl_xor(pv, m);
        }
        if (tcol == 0 && gr < n) { u[gr] = pu; v[gr] = pv; }
    }
}

// K1b: per-(group,sub) LDS histogram -> hsub[sub][node] (ushort, plain stores).
// Grid = GRPS*NSUB = 256 blocks x 1024 thr. Edge share MUST match k_scatter.
__global__ __launch_bounds__(1024) void k_hist(
    const int* __restrict__ ei, int E, int n, unsigned short* __restrict__ hsub)
{
    __shared__ unsigned hist[HCHUNK];
    int grp = blockIdx.x & (GRPS - 1);
    int sub = blockIdx.x / GRPS;
    int t = threadIdx.x;
    int lo = (int)((long long)grp * n / GRPS);
    int hi = (int)((long long)(grp + 1) * n / GRPS);
    for (int base = lo; base < hi; base += HCHUNK) {
        int clen = min(HCHUNK, hi - base);
        for (int i = t; i < clen; i += 1024) hist[i] = 0u;
        __syncthreads();
        for (int e = sub * 1024 + t; e < E; e += SUPER) {
            int s = ei[e];
            if (s >= base && s < base + clen) atomicAdd(&hist[s - base], 1u);
        }
        __syncthreads();
        for (int i = t; i < clen; i += 1024)
            hsub[(size_t)sub * n + base + i] = (unsigned short)hist[i];
        __syncthreads();
    }
}

// K2: per-256-node-block totals (1 self-loop + sum over subs) -> psum
__global__ void k_scan_partial(const unsigned short* __restrict__ hsub,
                               unsigned* __restrict__ psum, int n) {
    __shared__ unsigned s[256];
    int t = threadIdx.x, idx = blockIdx.x * 256 + t;
    unsigned c = 0u;
    if (idx < n) {
        c = 1u;
        for (int sb = 0; sb < NSUB; ++sb) c += hsub[(size_t)sb * n + idx];
    }
    s[t] = c;
    __syncthreads();
    for (int d = 128; d; d >>= 1) { if (t < d) s[t] += s[t + d]; __syncthreads(); }
    if (t == 0) psum[blockIdx.x] = s[0];
}

// K3: exclusive scan -> off; per-sub ushort DELTAS basepu (slot 0 = self-loop);
// packed self-loop entry {idx, w_self} written to edstP[off[idx]].
__global__ void k_scan_final(const unsigned* __restrict__ psum,
                             const unsigned short* __restrict__ hsub,
                             const float* __restrict__ u, const float* __restrict__ v,
                             const float* __restrict__ ab_p,
                             unsigned* __restrict__ off, unsigned short* __restrict__ basepu,
                             unsigned* __restrict__ edstP, int n) {
    __shared__ unsigned s[256];
    __shared__ unsigned wred[4];
    int t = threadIdx.x, idx = blockIdx.x * 256 + t;
    unsigned p = (t < blockIdx.x) ? psum[t] : 0u;
    p = waveSumU(p);
    if ((t & 63) == 0) wred[t >> 6] = p;
    __syncthreads();
    unsigned base = wred[0] + wred[1] + wred[2] + wred[3];

    unsigned run = 0u;
    if (idx < n) {
        run = 1u;                                  // slot 0: self-loop
        for (int sb = 0; sb < NSUB; ++sb) {
            basepu[(size_t)sb * n + idx] = (unsigned short)run;
            run += hsub[(size_t)sb * n + idx];
        }
    }
    s[t] = run; __syncthreads();
    for (int d = 1; d < 256; d <<= 1) {
        unsigned xx = (t >= d) ? s[t - d] : 0u;
        __syncthreads();
        s[t] += xx;
        __syncthreads();
    }
    unsigned excl = s[t] - run + base;
    if (idx < n) {
        off[idx] = excl;
        if (idx == n - 1) off[n] = excl + run;
        float wv = edgeW(u[idx], v[idx], ab_p[0]);
        unsigned short wh = __half_as_ushort(__float2half_rn(wv));
        edstP[excl] = (unsigned)idx | ((unsigned)wh << 16);   // n<=65536 required
    }
}

// K4: atomic-free scatter; packs {ushort d, half w} per edge. LDS cursors =
// off + basepu delta. Edge share per (grp,sub) MUST equal k_hist's share.
__global__ __launch_bounds__(1024) void k_scatter(
    const int* __restrict__ ei, int E, int n,
    const unsigned* __restrict__ off, const unsigned short* __restrict__ basepu,
    const float* __restrict__ u, const float* __restrict__ v,
    const float* __restrict__ ab_p, unsigned* __restrict__ edstP)
{
    __shared__ unsigned cur[HCHUNK];
    int grp = blockIdx.x & (GRPS - 1);
    int sub = blockIdx.x / GRPS;
    int t = threadIdx.x;
    float ab = ab_p[0];
    int lo = (int)((long long)grp * n / GRPS);
    int hi = (int)((long long)(grp + 1) * n / GRPS);
    for (int base = lo; base < hi; base += HCHUNK) {
        int clen = min(HCHUNK, hi - base);
        for (int i = t; i < clen; i += 1024)
            cur[i] = off[base + i] + basepu[(size_t)sub * n + base + i];
        __syncthreads();
        for (int e = sub * 1024 + t; e < E; e += SUPER) {
            int s = ei[e];
            int d = ei[E + e];               // coalesced, unconditional
            if (s >= base && s < base + clen) {
                float wv = edgeW(u[s], v[d], ab);
                unsigned short wh = __half_as_ushort(__float2half_rn(wv));
                unsigned p = atomicAdd(&cur[s - base], 1u);   // LDS atomic only
                edstP[p] = (unsigned)d | ((unsigned)wh << 16);
            }
        }
        __syncthreads();
    }
}

// K5: one WAVE per node, 4 nodes/block, barrier-free. Weights precomputed:
// pass1 = coalesced read + sum; pass2 = h gather + packed fp16 fma.
__global__ __launch_bounds__(256) void k_agg(
    const unsigned* __restrict__ edstP, const unsigned* __restrict__ off,
    const __half2* __restrict__ h2, float* __restrict__ out, int n)
{
    __shared__ unsigned ps[4][CAPW];
    int t = threadIdx.x;
    int wave = t >> 6, lane = t & 63;
    int i = blockIdx.x * 4 + wave;
    if (i >= n) return;
    unsigned s0 = off[i];
    int deg = (int)(off[i + 1] - s0);

    float sm = 0.f;
    for (int e = lane; e < deg; e += 64) {
        unsigned p = edstP[s0 + e];
        if (e < CAPW) ps[wave][e] = p;
        sm += __half2float(__ushort_as_half((unsigned short)(p >> 16)));
    }
    sm = waveSum(sm);
    float inv = 1.f / sm;

    int g = lane >> 4, gl = lane & 15;
    __half2 accA[4], accB[4];
    #pragma unroll
    for (int k = 0; k < 4; ++k) { accA[k] = __float2half2_rn(0.f); accB[k] = __float2half2_rn(0.f); }

    for (int e = g; e < deg; e += 8) {
        {
            unsigned p = (e < CAPW) ? ps[wave][e] : edstP[s0 + e];
            int d = (int)(p & 0xFFFFu);
            __half2 wh = __half2half2(__ushort_as_half((unsigned short)(p >> 16)));
            float4 raw = ((const float4*)(h2 + (size_t)d * 64))[gl];
            const __half2* hp = (const __half2*)&raw;
            #pragma unroll
            for (int k = 0; k < 4; ++k) accA[k] = __hfma2(wh, hp[k], accA[k]);
        }
        int e2 = e + 4;
        if (e2 < deg) {
            unsigned p = (e2 < CAPW) ? ps[wave][e2] : edstP[s0 + e2];
            int d = (int)(p & 0xFFFFu);
            __half2 wh = __half2half2(__ushort_as_half((unsigned short)(p >> 16)));
            float4 raw = ((const float4*)(h2 + (size_t)d * 64))[gl];
            const __half2* hp = (const __half2*)&raw;
            #pragma unroll
            for (int k = 0; k < 4; ++k) accB[k] = __hfma2(wh, hp[k], accB[k]);
        }
    }
    float acc[8];
    #pragma unroll
    for (int k = 0; k < 4; ++k) {
        float2 fa = __half22float2(accA[k]);
        float2 fb = __half22float2(accB[k]);
        acc[2 * k]     = fa.x + fb.x;
        acc[2 * k + 1] = fa.y + fb.y;
    }
    #pragma unroll
    for (int k = 0; k < 8; ++k) {
        acc[k] += __shfl_xor(acc[k], 16);
        acc[k] += __shfl_xor(acc[k], 32);
    }
    if (g == 0) {
        float o[8];
        #pragma unroll
        for (int k = 0; k < 8; ++k) {
            float z = acc[k] * inv;
            o[k] = z > 0.f ? z : expm1f(z);
        }
        float4* orow = (float4*)(out + (size_t)i * DH);
        orow[gl * 2]     = float4{o[0], o[1], o[2], o[3]};
        orow[gl * 2 + 1] = float4{o[4], o[5], o[6], o[7]};
    }
}

extern "C" void kernel_launch(void* const* d_in, const int* in_sizes, int n_in,
                              void* d_out, int out_size, void* d_ws, size_t ws_size,
                              hipStream_t stream) {
    const float* x  = (const float*)d_in[0];
    const int*   ei = (const int*)d_in[1];
    const float* W  = (const float*)d_in[2];
    const float* b  = (const float*)d_in[3];
    const float* a  = (const float*)d_in[4];
    const float* ab = (const float*)d_in[5];
    float* out = (float*)d_out;
    int n  = in_sizes[0] / DH;    // 50000 (packed ushort d requires n <= 65536)
    int E  = in_sizes[1] / 2;
    int ET = E + n;

    char* w = (char*)d_ws;
    __half2*        h2     = (__half2*)w;         w += (size_t)n * DH * 2;
    float*          u      = (float*)w;           w += (size_t)n * 4;
    float*          v      = (float*)w;           w += (size_t)n * 4;
    unsigned*       off    = (unsigned*)w;        w += (size_t)(n + 1) * 4 + 4;
    unsigned*       edstP  = (unsigned*)w;        w += (size_t)ET * 4;
    unsigned*       psum   = (unsigned*)w;        w += 4096;
    unsigned short* hsub   = (unsigned short*)w;  w += (size_t)NSUB * n * 2;
    unsigned short* basepu = (unsigned short*)w;  w += (size_t)NSUB * n * 2;

    int nb = (n + 63) / 64;
    k_matmul<<<nb, 256, 0, stream>>>(x, W, b, a, h2, u, v, n);

    // grid MUST be GRPS*NSUB (node-range groups x edge-share subs)
    k_hist<<<GRPS * NSUB, 1024, 0, stream>>>(ei, E, n, hsub);

    int B = (n + 255) / 256;
    k_scan_partial<<<B, 256, 0, stream>>>(hsub, psum, n);
    k_scan_final<<<B, 256, 0, stream>>>(psum, hsub, u, v, ab, off, basepu, edstP, n);

    // same grid/share pattern as k_hist
    k_scatter<<<GRPS * NSUB, 1024, 0, stream>>>(ei, E, n, off, basepu, u, v, ab, edstP);

    k_agg<<<(n + 3) / 4, 256, 0, stream>>>(edstP, off, h2, out, n);
}

// Round 14
// 136.736 us; speedup vs baseline: 1.2503x; 1.0782x over previous
//
#include <hip/hip_runtime.h>
#include <hip/hip_fp16.h>
#include <math.h>

#define DH 128
#define CAPW 128
#define GRPS 4
#define NSUB 64
#define SUPER (NSUB * 1024)    // 65536: edge-share super-block (hist & scatter MUST match)
#define HCHUNK 12800

typedef _Float16 f16x8 __attribute__((ext_vector_type(8)));
typedef float    f32x4 __attribute__((ext_vector_type(4)));

__device__ __forceinline__ float waveSum(float x) {
    #pragma unroll
    for (int m = 32; m; m >>= 1) x += __shfl_xor(x, m);
    return x;
}
__device__ __forceinline__ unsigned waveSumU(unsigned x) {
    #pragma unroll
    for (int m = 32; m; m >>= 1) x += __shfl_xor(x, m);
    return x;
}

__device__ __forceinline__ float edgeW(float ui, float vd, float ab) {
    float C = fmaxf(ui + ab, 0.f);
    float lg = ui + vd + ab;
    lg = lg >= 0.f ? lg : 0.01f * lg;
    return __expf(fminf(lg - C, 10.f));
}

// K1: MFMA GEMM: h = x@W + b. 64 rows/block, 4 waves; wave w owns rows 16w..16w+15.
// A frag: lane holds X[row0+ (l&15)][k=(ks*32)+(l>>4)*8+j] -> contiguous 16B in Xs2.
// B frag: lane holds W[k][col=(j*16)+(l&15)] -> Wtp stores W TRANSPOSED so the read
//         Wtp[col][k2=ks*16+(l>>4)*4 ..+4] is contiguous 16B.
// C/D: col=lane&15, row=(lane>>4)*4+reg  [verified layout, m89/m91].
// Epilogue: acc(+b) -> LDS (Xs2 reused after barrier) -> coalesced h store + u,v dots.
__global__ __launch_bounds__(256) void k_matmul(
    const float* __restrict__ x, const float* __restrict__ Wg,
    const float* __restrict__ bg, const float* __restrict__ ag,
    __half2* __restrict__ h2, float* __restrict__ u, float* __restrict__ v, int n)
{
    __shared__ __half2 Wtp[128][68];   // Wtp[c][k2] = {W[2k2][c], W[2k2+1][c]}  34.8 KB
    __shared__ __half2 Xs2[64][68];    // in: {x[r][2k2],x[r][2k2+1]}; out: h row (fp16)  17.4 KB
    __shared__ float as_s[128], ad_s[128];
    int t = threadIdx.x;
    int row0 = blockIdx.x * 64;

    const float4* W4 = (const float4*)Wg;
    for (int i = t; i < 2048; i += 256) {      // i = k2*32 + c4
        int k2 = i >> 5, c4 = i & 31;
        float4 a = W4[(2 * k2) * 32 + c4];
        float4 b = W4[(2 * k2 + 1) * 32 + c4];
        Wtp[c4 * 4 + 0][k2] = __floats2half2_rn(a.x, b.x);
        Wtp[c4 * 4 + 1][k2] = __floats2half2_rn(a.y, b.y);
        Wtp[c4 * 4 + 2][k2] = __floats2half2_rn(a.z, b.z);
        Wtp[c4 * 4 + 3][k2] = __floats2half2_rn(a.w, b.w);
    }
    const float4* x4 = (const float4*)x;
    for (int i = t; i < 2048; i += 256) {      // i = r*32 + c4
        int r = i >> 5, c4 = i & 31;
        int gr = row0 + r;
        float4 xv = (gr < n) ? x4[(size_t)gr * 32 + c4] : float4{0.f, 0.f, 0.f, 0.f};
        Xs2[r][c4 * 2]     = __floats2half2_rn(xv.x, xv.y);
        Xs2[r][c4 * 2 + 1] = __floats2half2_rn(xv.z, xv.w);
    }
    if (t < 128) { as_s[t] = ag[t]; ad_s[t] = ag[128 + t]; }
    __syncthreads();

    int wv = t >> 6, l = t & 63;
    int m = l & 15, g = l >> 4;
    int r0 = wv * 16;

    f16x8 afr[4];
    #pragma unroll
    for (int ks = 0; ks < 4; ++ks)
        afr[ks] = *(const f16x8*)&Xs2[r0 + m][ks * 16 + g * 4];

    f32x4 accv[8];
    #pragma unroll
    for (int j = 0; j < 8; ++j) accv[j] = (f32x4){0.f, 0.f, 0.f, 0.f};

    #pragma unroll
    for (int j = 0; j < 8; ++j) {               // col tile n0 = j*16
        #pragma unroll
        for (int ks = 0; ks < 4; ++ks) {
            f16x8 bfr = *(const f16x8*)&Wtp[j * 16 + m][ks * 16 + g * 4];
            accv[j] = __builtin_amdgcn_mfma_f32_16x16x32_f16(afr[ks], bfr, accv[j], 0, 0, 0);
        }
    }
    __syncthreads();   // Xs2 x-data fully consumed; reuse as h-row staging

    __half* hs = (__half*)Xs2;                  // row stride 136 half (272 B, 16B-aligned)
    #pragma unroll
    for (int j = 0; j < 8; ++j) {
        int cc = j * 16 + m;
        float bv = bg[cc];
        #pragma unroll
        for (int rg = 0; rg < 4; ++rg) {
            int rr = r0 + g * 4 + rg;
            hs[rr * 136 + cc] = __float2half_rn(accv[j][rg] + bv);
        }
    }
    __syncthreads();

    // coalesced h store
    for (int i = t; i < 1024; i += 256) {       // i = r*16 + c8 (16B chunks)
        int r = i >> 4, c8 = i & 15;
        int gr = row0 + r;
        if (gr < n)
            ((float4*)h2)[(size_t)gr * 16 + c8] =
                *(const float4*)((const char*)Xs2 + r * 272 + c8 * 16);
    }
    // u,v: 4 threads per row, 32 cols each, reduce over lanes {1,2}
    int ur = t >> 2, useg = t & 3;
    float su = 0.f, sv = 0.f;
    const __half2* xr = &Xs2[ur][useg * 16];
    #pragma unroll
    for (int j = 0; j < 16; ++j) {
        float2 f = __half22float2(xr[j]);
        int k = useg * 32 + 2 * j;
        su += f.x * as_s[k] + f.y * as_s[k + 1];
        sv += f.x * ad_s[k] + f.y * ad_s[k + 1];
    }
    su += __shfl_xor(su, 1); su += __shfl_xor(su, 2);
    sv += __shfl_xor(sv, 1); sv += __shfl_xor(sv, 2);
    int gr = row0 + ur;
    if (useg == 0 && gr < n) { u[gr] = su; v[gr] = sv; }
}

// K1b: per-(group,sub) LDS histogram -> hsub[sub][node] (ushort, plain stores).
// Grid = GRPS*NSUB = 256 blocks x 1024 thr. Edge share MUST match k_scatter.
__global__ __launch_bounds__(1024) void k_hist(
    const int* __restrict__ ei, int E, int n, unsigned short* __restrict__ hsub)
{
    __shared__ unsigned hist[HCHUNK];
    int grp = blockIdx.x & (GRPS - 1);
    int sub = blockIdx.x / GRPS;
    int t = threadIdx.x;
    int lo = (int)((long long)grp * n / GRPS);
    int hi = (int)((long long)(grp + 1) * n / GRPS);
    for (int base = lo; base < hi; base += HCHUNK) {
        int clen = min(HCHUNK, hi - base);
        for (int i = t; i < clen; i += 1024) hist[i] = 0u;
        __syncthreads();
        for (int e = sub * 1024 + t; e < E; e += SUPER) {
            int s = ei[e];
            if (s >= base && s < base + clen) atomicAdd(&hist[s - base], 1u);
        }
        __syncthreads();
        for (int i = t; i < clen; i += 1024)
            hsub[(size_t)sub * n + base + i] = (unsigned short)hist[i];
        __syncthreads();
    }
}

// K2: per-256-node-block totals (1 self-loop + sum over subs) -> psum
__global__ void k_scan_partial(const unsigned short* __restrict__ hsub,
                               unsigned* __restrict__ psum, int n) {
    __shared__ unsigned s[256];
    int t = threadIdx.x, idx = blockIdx.x * 256 + t;
    unsigned c = 0u;
    if (idx < n) {
        c = 1u;
        for (int sb = 0; sb < NSUB; ++sb) c += hsub[(size_t)sb * n + idx];
    }
    s[t] = c;
    __syncthreads();
    for (int d = 128; d; d >>= 1) { if (t < d) s[t] += s[t + d]; __syncthreads(); }
    if (t == 0) psum[blockIdx.x] = s[0];
}

// K3: exclusive scan -> off; per-sub ushort DELTAS basepu (slot 0 = self-loop);
// packed self-loop entry {idx, w_self} written to edstP[off[idx]].
__global__ void k_scan_final(const unsigned* __restrict__ psum,
                             const unsigned short* __restrict__ hsub,
                             const float* __restrict__ u, const float* __restrict__ v,
                             const float* __restrict__ ab_p,
                             unsigned* __restrict__ off, unsigned short* __restrict__ basepu,
                             unsigned* __restrict__ edstP, int n) {
    __shared__ unsigned s[256];
    __shared__ unsigned wred[4];
    int t = threadIdx.x, idx = blockIdx.x * 256 + t;
    unsigned p = (t < blockIdx.x) ? psum[t] : 0u;
    p = waveSumU(p);
    if ((t & 63) == 0) wred[t >> 6] = p;
    __syncthreads();
    unsigned base = wred[0] + wred[1] + wred[2] + wred[3];

    unsigned run = 0u;
    if (idx < n) {
        run = 1u;                                  // slot 0: self-loop
        for (int sb = 0; sb < NSUB; ++sb) {
            basepu[(size_t)sb * n + idx] = (unsigned short)run;
            run += hsub[(size_t)sb * n + idx];
        }
    }
    s[t] = run; __syncthreads();
    for (int d = 1; d < 256; d <<= 1) {
        unsigned xx = (t >= d) ? s[t - d] : 0u;
        __syncthreads();
        s[t] += xx;
        __syncthreads();
    }
    unsigned excl = s[t] - run + base;
    if (idx < n) {
        off[idx] = excl;
        if (idx == n - 1) off[n] = excl + run;
        float wv = edgeW(u[idx], v[idx], ab_p[0]);
        unsigned short wh = __half_as_ushort(__float2half_rn(wv));
        edstP[excl] = (unsigned)idx | ((unsigned)wh << 16);   // n<=65536 required
    }
}

// K4: atomic-free scatter; packs {ushort d, half w} per edge. LDS cursors =
// off + basepu delta. Edge share per (grp,sub) MUST equal k_hist's share.
__global__ __launch_bounds__(1024) void k_scatter(
    const int* __restrict__ ei, int E, int n,
    const unsigned* __restrict__ off, const unsigned short* __restrict__ basepu,
    const float* __restrict__ u, const float* __restrict__ v,
    const float* __restrict__ ab_p, unsigned* __restrict__ edstP)
{
    __shared__ unsigned cur[HCHUNK];
    int grp = blockIdx.x & (GRPS - 1);
    int sub = blockIdx.x / GRPS;
    int t = threadIdx.x;
    float ab = ab_p[0];
    int lo = (int)((long long)grp * n / GRPS);
    int hi = (int)((long long)(grp + 1) * n / GRPS);
    for (int base = lo; base < hi; base += HCHUNK) {
        int clen = min(HCHUNK, hi - base);
        for (int i = t; i < clen; i += 1024)
            cur[i] = off[base + i] + basepu[(size_t)sub * n + base + i];
        __syncthreads();
        for (int e = sub * 1024 + t; e < E; e += SUPER) {
            int s = ei[e];
            int d = ei[E + e];               // coalesced, unconditional
            if (s >= base && s < base + clen) {
                float wv = edgeW(u[s], v[d], ab);
                unsigned short wh = __half_as_ushort(__float2half_rn(wv));
                unsigned p = atomicAdd(&cur[s - base], 1u);   // LDS atomic only
                edstP[p] = (unsigned)d | ((unsigned)wh << 16);
            }
        }
        __syncthreads();
    }
}

// K5: one WAVE per node, 4 nodes/block, barrier-free. Weights precomputed:
// pass1 = coalesced read + sum; pass2 = h gather + packed fp16 fma.
__global__ __launch_bounds__(256) void k_agg(
    const unsigned* __restrict__ edstP, const unsigned* __restrict__ off,
    const __half2* __restrict__ h2, float* __restrict__ out, int n)
{
    __shared__ unsigned ps[4][CAPW];
    int t = threadIdx.x;
    int wave = t >> 6, lane = t & 63;
    int i = blockIdx.x * 4 + wave;
    if (i >= n) return;
    unsigned s0 = off[i];
    int deg = (int)(off[i + 1] - s0);

    float sm = 0.f;
    for (int e = lane; e < deg; e += 64) {
        unsigned p = edstP[s0 + e];
        if (e < CAPW) ps[wave][e] = p;
        sm += __half2float(__ushort_as_half((unsigned short)(p >> 16)));
    }
    sm = waveSum(sm);
    float inv = 1.f / sm;

    int g = lane >> 4, gl = lane & 15;
    __half2 accA[4], accB[4];
    #pragma unroll
    for (int k = 0; k < 4; ++k) { accA[k] = __float2half2_rn(0.f); accB[k] = __float2half2_rn(0.f); }

    for (int e = g; e < deg; e += 8) {
        {
            unsigned p = (e < CAPW) ? ps[wave][e] : edstP[s0 + e];
            int d = (int)(p & 0xFFFFu);
            __half2 wh = __half2half2(__ushort_as_half((unsigned short)(p >> 16)));
            float4 raw = ((const float4*)(h2 + (size_t)d * 64))[gl];
            const __half2* hp = (const __half2*)&raw;
            #pragma unroll
            for (int k = 0; k < 4; ++k) accA[k] = __hfma2(wh, hp[k], accA[k]);
        }
        int e2 = e + 4;
        if (e2 < deg) {
            unsigned p = (e2 < CAPW) ? ps[wave][e2] : edstP[s0 + e2];
            int d = (int)(p & 0xFFFFu);
            __half2 wh = __half2half2(__ushort_as_half((unsigned short)(p >> 16)));
            float4 raw = ((const float4*)(h2 + (size_t)d * 64))[gl];
            const __half2* hp = (const __half2*)&raw;
            #pragma unroll
            for (int k = 0; k < 4; ++k) accB[k] = __hfma2(wh, hp[k], accB[k]);
        }
    }
    float acc[8];
    #pragma unroll
    for (int k = 0; k < 4; ++k) {
        float2 fa = __half22float2(accA[k]);
        float2 fb = __half22float2(accB[k]);
        acc[2 * k]     = fa.x + fb.x;
        acc[2 * k + 1] = fa.y + fb.y;
    }
    #pragma unroll
    for (int k = 0; k < 8; ++k) {
        acc[k] += __shfl_xor(acc[k], 16);
        acc[k] += __shfl_xor(acc[k], 32);
    }
    if (g == 0) {
        float o[8];
        #pragma unroll
        for (int k = 0; k < 8; ++k) {
            float z = acc[k] * inv;
            o[k] = z > 0.f ? z : expm1f(z);
        }
        float4* orow = (float4*)(out + (size_t)i * DH);
        orow[gl * 2]     = float4{o[0], o[1], o[2], o[3]};
        orow[gl * 2 + 1] = float4{o[4], o[5], o[6], o[7]};
    }
}

extern "C" void kernel_launch(void* const* d_in, const int* in_sizes, int n_in,
                              void* d_out, int out_size, void* d_ws, size_t ws_size,
                              hipStream_t stream) {
    const float* x  = (const float*)d_in[0];
    const int*   ei = (const int*)d_in[1];
    const float* W  = (const float*)d_in[2];
    const float* b  = (const float*)d_in[3];
    const float* a  = (const float*)d_in[4];
    const float* ab = (const float*)d_in[5];
    float* out = (float*)d_out;
    int n  = in_sizes[0] / DH;    // 50000 (packed ushort d requires n <= 65536)
    int E  = in_sizes[1] / 2;
    int ET = E + n;

    char* w = (char*)d_ws;
    __half2*        h2     = (__half2*)w;         w += (size_t)n * DH * 2;
    float*          u      = (float*)w;           w += (size_t)n * 4;
    float*          v      = (float*)w;           w += (size_t)n * 4;
    unsigned*       off    = (unsigned*)w;        w += (size_t)(n + 1) * 4 + 4;
    unsigned*       edstP  = (unsigned*)w;        w += (size_t)ET * 4;
    unsigned*       psum   = (unsigned*)w;        w += 4096;
    unsigned short* hsub   = (unsigned short*)w;  w += (size_t)NSUB * n * 2;
    unsigned short* basepu = (unsigned short*)w;  w += (size_t)NSUB * n * 2;

    int nb = (n + 63) / 64;
    k_matmul<<<nb, 256, 0, stream>>>(x, W, b, a, h2, u, v, n);

    // grid MUST be GRPS*NSUB (node-range groups x edge-share subs)
    k_hist<<<GRPS * NSUB, 1024, 0, stream>>>(ei, E, n, hsub);

    int B = (n + 255) / 256;
    k_scan_partial<<<B, 256, 0, stream>>>(hsub, psum, n);
    k_scan_final<<<B, 256, 0, stream>>>(psum, hsub, u, v, ab, off, basepu, edstP, n);

    // same grid/share pattern as k_hist
    k_scatter<<<GRPS * NSUB, 1024, 0, stream>>>(ei, E, n, off, basepu, u, v, ab, edstP);

    k_agg<<<(n + 3) / 4, 256, 0, stream>>>(edstP, off, h2, out, n);
}

// Round 15
// 132.202 us; speedup vs baseline: 1.2932x; 1.0343x over previous
//
#include <hip/hip_runtime.h>
#include <hip/hip_fp16.h>
#include <math.h>

#define DH 128
#define CAPW 128
#define GRPS 4
#define NSUB 64
#define SUPER (NSUB * 1024)    // 65536: edge-share super-block (hist & scatter MUST match)
#define HCHUNK 12800

typedef _Float16 f16x8 __attribute__((ext_vector_type(8)));
typedef float    f32x4 __attribute__((ext_vector_type(4)));

__device__ __forceinline__ float waveSum(float x) {
    #pragma unroll
    for (int m = 32; m; m >>= 1) x += __shfl_xor(x, m);
    return x;
}
__device__ __forceinline__ unsigned waveSumU(unsigned x) {
    #pragma unroll
    for (int m = 32; m; m >>= 1) x += __shfl_xor(x, m);
    return x;
}

__device__ __forceinline__ float edgeW(float ui, float vd, float ab) {
    float C = fmaxf(ui + ab, 0.f);
    float lg = ui + vd + ab;
    lg = lg >= 0.f ? lg : 0.01f * lg;
    return __expf(fminf(lg - C, 10.f));
}

// K1: MFMA GEMM: h = x@W + b. 64 rows/block, 4 waves; wave w owns rows 16w..16w+15.
// Also zeroes the scan's ready[] flags (block 0, plain stores; visible to the scan
// kernel via kernel-boundary cache flush).
__global__ __launch_bounds__(256) void k_matmul(
    const float* __restrict__ x, const float* __restrict__ Wg,
    const float* __restrict__ bg, const float* __restrict__ ag,
    __half2* __restrict__ h2, float* __restrict__ u, float* __restrict__ v,
    unsigned* __restrict__ ready, int n)
{
    __shared__ __half2 Wtp[128][68];   // Wtp[c][k2] = {W[2k2][c], W[2k2+1][c]}
    __shared__ __half2 Xs2[64][68];    // in: x rows (fp16 k-pairs); out: h rows
    __shared__ float as_s[128], ad_s[128];
    int t = threadIdx.x;
    int row0 = blockIdx.x * 64;
    if (blockIdx.x == 0) ready[t] = 0u;   // reset lookback flags each launch

    const float4* W4 = (const float4*)Wg;
    for (int i = t; i < 2048; i += 256) {      // i = k2*32 + c4
        int k2 = i >> 5, c4 = i & 31;
        float4 a = W4[(2 * k2) * 32 + c4];
        float4 b = W4[(2 * k2 + 1) * 32 + c4];
        Wtp[c4 * 4 + 0][k2] = __floats2half2_rn(a.x, b.x);
        Wtp[c4 * 4 + 1][k2] = __floats2half2_rn(a.y, b.y);
        Wtp[c4 * 4 + 2][k2] = __floats2half2_rn(a.z, b.z);
        Wtp[c4 * 4 + 3][k2] = __floats2half2_rn(a.w, b.w);
    }
    const float4* x4 = (const float4*)x;
    for (int i = t; i < 2048; i += 256) {      // i = r*32 + c4
        int r = i >> 5, c4 = i & 31;
        int gr = row0 + r;
        float4 xv = (gr < n) ? x4[(size_t)gr * 32 + c4] : float4{0.f, 0.f, 0.f, 0.f};
        Xs2[r][c4 * 2]     = __floats2half2_rn(xv.x, xv.y);
        Xs2[r][c4 * 2 + 1] = __floats2half2_rn(xv.z, xv.w);
    }
    if (t < 128) { as_s[t] = ag[t]; ad_s[t] = ag[128 + t]; }
    __syncthreads();

    int wv = t >> 6, l = t & 63;
    int m = l & 15, g = l >> 4;
    int r0 = wv * 16;

    f16x8 afr[4];
    #pragma unroll
    for (int ks = 0; ks < 4; ++ks)
        afr[ks] = *(const f16x8*)&Xs2[r0 + m][ks * 16 + g * 4];

    f32x4 accv[8];
    #pragma unroll
    for (int j = 0; j < 8; ++j) accv[j] = (f32x4){0.f, 0.f, 0.f, 0.f};

    #pragma unroll
    for (int j = 0; j < 8; ++j) {               // col tile n0 = j*16
        #pragma unroll
        for (int ks = 0; ks < 4; ++ks) {
            f16x8 bfr = *(const f16x8*)&Wtp[j * 16 + m][ks * 16 + g * 4];
            accv[j] = __builtin_amdgcn_mfma_f32_16x16x32_f16(afr[ks], bfr, accv[j], 0, 0, 0);
        }
    }
    __syncthreads();   // Xs2 x-data fully consumed; reuse as h-row staging

    __half* hs = (__half*)Xs2;                  // row stride 136 half (272 B)
    #pragma unroll
    for (int j = 0; j < 8; ++j) {
        int cc = j * 16 + m;
        float bv = bg[cc];
        #pragma unroll
        for (int rg = 0; rg < 4; ++rg) {
            int rr = r0 + g * 4 + rg;
            hs[rr * 136 + cc] = __float2half_rn(accv[j][rg] + bv);
        }
    }
    __syncthreads();

    // coalesced h store
    for (int i = t; i < 1024; i += 256) {       // i = r*16 + c8 (16B chunks)
        int r = i >> 4, c8 = i & 15;
        int gr = row0 + r;
        if (gr < n)
            ((float4*)h2)[(size_t)gr * 16 + c8] =
                *(const float4*)((const char*)Xs2 + r * 272 + c8 * 16);
    }
    // u,v: 4 threads per row, 32 cols each, reduce over lanes {1,2}
    int ur = t >> 2, useg = t & 3;
    float su = 0.f, sv = 0.f;
    const __half2* xr = &Xs2[ur][useg * 16];
    #pragma unroll
    for (int j = 0; j < 16; ++j) {
        float2 f = __half22float2(xr[j]);
        int k = useg * 32 + 2 * j;
        su += f.x * as_s[k] + f.y * as_s[k + 1];
        sv += f.x * ad_s[k] + f.y * ad_s[k + 1];
    }
    su += __shfl_xor(su, 1); su += __shfl_xor(su, 2);
    sv += __shfl_xor(sv, 1); sv += __shfl_xor(sv, 2);
    int gr = row0 + ur;
    if (useg == 0 && gr < n) { u[gr] = su; v[gr] = sv; }
}

// K1b: per-(group,sub) LDS histogram -> hsub[sub][node] (ushort, plain stores).
// Grid = GRPS*NSUB = 256 blocks x 1024 thr. Edge share MUST match k_scatter.
__global__ __launch_bounds__(1024) void k_hist(
    const int* __restrict__ ei, int E, int n, unsigned short* __restrict__ hsub)
{
    __shared__ unsigned hist[HCHUNK];
    int grp = blockIdx.x & (GRPS - 1);
    int sub = blockIdx.x / GRPS;
    int t = threadIdx.x;
    int lo = (int)((long long)grp * n / GRPS);
    int hi = (int)((long long)(grp + 1) * n / GRPS);
    for (int base = lo; base < hi; base += HCHUNK) {
        int clen = min(HCHUNK, hi - base);
        for (int i = t; i < clen; i += 1024) hist[i] = 0u;
        __syncthreads();
        for (int e = sub * 1024 + t; e < E; e += SUPER) {
            int s = ei[e];
            if (s >= base && s < base + clen) atomicAdd(&hist[s - base], 1u);
        }
        __syncthreads();
        for (int i = t; i < clen; i += 1024)
            hsub[(size_t)sub * n + base + i] = (unsigned short)hist[i];
        __syncthreads();
    }
}

// K2: SINGLE-KERNEL scan (decoupled lookback). Each block: per-node totals +
// per-sub ushort deltas basepu (slot 0 = self-loop), local scan, publish
// inclusive total (bit31 = ready) via atomicExch, poll predecessors with
// atomic reads, wave-reduce bases. All blocks co-resident (B <= 256).
// Self-loop entry edst[off[idx]] = idx.
__global__ __launch_bounds__(256) void k_scan(
    const unsigned short* __restrict__ hsub, unsigned* __restrict__ ready,
    unsigned* __restrict__ off, unsigned short* __restrict__ basepu,
    int* __restrict__ edst, int n)
{
    __shared__ unsigned s[256];
    __shared__ unsigned wred[4];
    int t = threadIdx.x, bid = blockIdx.x, idx = bid * 256 + t;

    unsigned run = 0u;
    if (idx < n) {
        run = 1u;                                  // slot 0: self-loop
        for (int sb = 0; sb < NSUB; ++sb) {
            basepu[(size_t)sb * n + idx] = (unsigned short)run;
            run += hsub[(size_t)sb * n + idx];
        }
    }
    s[t] = run; __syncthreads();
    for (int d = 1; d < 256; d <<= 1) {
        unsigned xx = (t >= d) ? s[t - d] : 0u;
        __syncthreads();
        s[t] += xx;
        __syncthreads();
    }
    if (t == 255) {                               // publish inclusive block total
        __threadfence();
        atomicExch(&ready[bid], 0x80000000u | s[255]);
    }
    unsigned p = 0u;
    if (t < bid) {                                // poll predecessor t
        unsigned val;
        do { val = atomicAdd(&ready[t], 0u); } while (!(val & 0x80000000u));
        p = val & 0x7FFFFFFFu;
    }
    p = waveSumU(p);
    if ((t & 63) == 0) wred[t >> 6] = p;
    __syncthreads();
    unsigned base = wred[0] + wred[1] + wred[2] + wred[3];

    unsigned excl = s[t] - run + base;
    if (idx < n) {
        off[idx] = excl;
        if (idx == n - 1) off[n] = excl + run;
        edst[excl] = idx;                          // self-loop occupies slot 0
    }
}

// K4: atomic-free scatter, PLAIN d stores (weights computed in k_agg — measured
// equal there, and it removes u/v gathers + exp from this kernel). LDS cursors =
// off + basepu delta. Edge share per (grp,sub) MUST equal k_hist's share.
__global__ __launch_bounds__(1024) void k_scatter(
    const int* __restrict__ ei, int E, int n,
    const unsigned* __restrict__ off, const unsigned short* __restrict__ basepu,
    int* __restrict__ edst)
{
    __shared__ unsigned cur[HCHUNK];
    int grp = blockIdx.x & (GRPS - 1);
    int sub = blockIdx.x / GRPS;
    int t = threadIdx.x;
    int lo = (int)((long long)grp * n / GRPS);
    int hi = (int)((long long)(grp + 1) * n / GRPS);
    for (int base = lo; base < hi; base += HCHUNK) {
        int clen = min(HCHUNK, hi - base);
        for (int i = t; i < clen; i += 1024)
            cur[i] = off[base + i] + basepu[(size_t)sub * n + base + i];
        __syncthreads();
        for (int e = sub * 1024 + t; e < E; e += SUPER) {
            int s = ei[e];
            int d = ei[E + e];               // coalesced, unconditional
            if (s >= base && s < base + clen) {
                unsigned p = atomicAdd(&cur[s - base], 1u);   // LDS atomic only
                edst[p] = d;
            }
        }
        __syncthreads();
    }
}

// K5: one WAVE per node, 4 nodes/block, barrier-free. Pass1: edst read + v[d]
// gather (L2-resident 200KB) + edgeW (C-shift, clamp 10 for fp16 range), stash
// {d, w} in LDS. Pass2: h gather + packed fp16 fma, dual accumulators.
__global__ __launch_bounds__(256) void k_agg(
    const int* __restrict__ edst, const unsigned* __restrict__ off,
    const __half2* __restrict__ h2, const float* __restrict__ u,
    const float* __restrict__ v, const float* __restrict__ ab_p,
    float* __restrict__ out, int n)
{
    __shared__ float ex_s[4][CAPW];
    __shared__ int   ds_s[4][CAPW];
    int t = threadIdx.x;
    int wave = t >> 6, lane = t & 63;
    int i = blockIdx.x * 4 + wave;
    if (i >= n) return;
    unsigned s0 = off[i];
    int deg = (int)(off[i + 1] - s0);
    float ab = ab_p[0];
    float ui = u[i];

    float sm = 0.f;
    for (int e = lane; e < deg; e += 64) {
        int d = edst[s0 + e];
        float w = edgeW(ui, v[d], ab);
        if (e < CAPW) { ds_s[wave][e] = d; ex_s[wave][e] = w; }
        sm += w;
    }
    sm = waveSum(sm);
    float inv = 1.f / sm;

    int g = lane >> 4, gl = lane & 15;
    __half2 accA[4], accB[4];
    #pragma unroll
    for (int k = 0; k < 4; ++k) { accA[k] = __float2half2_rn(0.f); accB[k] = __float2half2_rn(0.f); }

    for (int e = g; e < deg; e += 8) {
        {
            float w; int d;
            if (e < CAPW) { w = ex_s[wave][e]; d = ds_s[wave][e]; }
            else          { d = edst[s0 + e]; w = edgeW(ui, v[d], ab); }
            __half2 wh = __float2half2_rn(w);
            float4 raw = ((const float4*)(h2 + (size_t)d * 64))[gl];
            const __half2* hp = (const __half2*)&raw;
            #pragma unroll
            for (int k = 0; k < 4; ++k) accA[k] = __hfma2(wh, hp[k], accA[k]);
        }
        int e2 = e + 4;
        if (e2 < deg) {
            float w; int d;
            if (e2 < CAPW) { w = ex_s[wave][e2]; d = ds_s[wave][e2]; }
            else           { d = edst[s0 + e2]; w = edgeW(ui, v[d], ab); }
            __half2 wh = __float2half2_rn(w);
            float4 raw = ((const float4*)(h2 + (size_t)d * 64))[gl];
            const __half2* hp = (const __half2*)&raw;
            #pragma unroll
            for (int k = 0; k < 4; ++k) accB[k] = __hfma2(wh, hp[k], accB[k]);
        }
    }
    float acc[8];
    #pragma unroll
    for (int k = 0; k < 4; ++k) {
        float2 fa = __half22float2(accA[k]);
        float2 fb = __half22float2(accB[k]);
        acc[2 * k]     = fa.x + fb.x;
        acc[2 * k + 1] = fa.y + fb.y;
    }
    #pragma unroll
    for (int k = 0; k < 8; ++k) {
        acc[k] += __shfl_xor(acc[k], 16);
        acc[k] += __shfl_xor(acc[k], 32);
    }
    if (g == 0) {
        float o[8];
        #pragma unroll
        for (int k = 0; k < 8; ++k) {
            float z = acc[k] * inv;
            o[k] = z > 0.f ? z : expm1f(z);
        }
        float4* orow = (float4*)(out + (size_t)i * DH);
        orow[gl * 2]     = float4{o[0], o[1], o[2], o[3]};
        orow[gl * 2 + 1] = float4{o[4], o[5], o[6], o[7]};
    }
}

extern "C" void kernel_launch(void* const* d_in, const int* in_sizes, int n_in,
                              void* d_out, int out_size, void* d_ws, size_t ws_size,
                              hipStream_t stream) {
    const float* x  = (const float*)d_in[0];
    const int*   ei = (const int*)d_in[1];
    const float* W  = (const float*)d_in[2];
    const float* b  = (const float*)d_in[3];
    const float* a  = (const float*)d_in[4];
    const float* ab = (const float*)d_in[5];
    float* out = (float*)d_out;
    int n  = in_sizes[0] / DH;    // 50000 (lookback scan requires n <= 65536)
    int E  = in_sizes[1] / 2;
    int ET = E + n;

    char* w = (char*)d_ws;
    __half2*        h2     = (__half2*)w;         w += (size_t)n * DH * 2;
    float*          u      = (float*)w;           w += (size_t)n * 4;
    float*          v      = (float*)w;           w += (size_t)n * 4;
    unsigned*       off    = (unsigned*)w;        w += (size_t)(n + 1) * 4 + 4;
    int*            edst   = (int*)w;             w += (size_t)ET * 4;
    unsigned*       ready  = (unsigned*)w;        w += 4096;
    unsigned short* hsub   = (unsigned short*)w;  w += (size_t)NSUB * n * 2;
    unsigned short* basepu = (unsigned short*)w;  w += (size_t)NSUB * n * 2;

    int nb = (n + 63) / 64;
    k_matmul<<<nb, 256, 0, stream>>>(x, W, b, a, h2, u, v, ready, n);

    // grid MUST be GRPS*NSUB (node-range groups x edge-share subs)
    k_hist<<<GRPS * NSUB, 1024, 0, stream>>>(ei, E, n, hsub);

    int B = (n + 255) / 256;
    k_scan<<<B, 256, 0, stream>>>(hsub, ready, off, basepu, edst, n);

    // same grid/share pattern as k_hist
    k_scatter<<<GRPS * NSUB, 1024, 0, stream>>>(ei, E, n, off, basepu, edst);

    k_agg<<<(n + 3) / 4, 256, 0, stream>>>(edst, off, h2, u, v, ab, out, n);
}